// Round 11
// baseline (627.086 us; speedup 1.0000x reference)
//
#include <hip/hip_runtime.h>
#include <cstdint>
#include <cstddef>

#define BSZ    32
#define SEQL   2048
#define ENCD   512
#define DE     1024   // DEC + ENC
#define NHEADS 8
#define IHD    1024   // INTERM * HEADS

typedef unsigned short u16;
typedef __bf16 bf16x8 __attribute__((ext_vector_type(8)));
typedef float floatx4 __attribute__((ext_vector_type(4)));
typedef unsigned short u16x8 __attribute__((ext_vector_type(8)));

__device__ __forceinline__ u16 f2bf(float f) {
    unsigned int u = __float_as_uint(f);
    u = (u + 0x7FFFu + ((u >> 16) & 1u)) >> 16;   // RNE
    return (u16)u;
}
__device__ __forceinline__ float bf2f(u16 v) {
    return __uint_as_float(((unsigned int)v) << 16);
}
__device__ __forceinline__ float softplus_f(float x) {
    return fmaxf(x, 0.0f) + log1pf(__expf(-fabsf(x)));
}
__device__ __forceinline__ float tanh_fast(float x) {
    const float e = __expf(2.0f * x);
    return 1.0f - 2.0f / (e + 1.0f);
}
__device__ __forceinline__ void async_cp16(u16* lds, const u16* g) {
    __builtin_amdgcn_global_load_lds(
        (const __attribute__((address_space(1))) unsigned int*)g,
        (__attribute__((address_space(3))) unsigned int*)lds, 16, 0, 0);
}

// ---------------------------------------------------------------------------
// Producer kernel (unchanged, measured):
//   bid <  128 : WvT[n][k] = bf16(Wv[k][n]) via 64x64 LDS tile transpose
//   bid == 128 : Wf -> bf16 packed in MFMA B-fragment order
//   bid >  128 : prep (query_ws = dec@Wq+bq+bv, beta, kappa), 32x33 blocks
// ---------------------------------------------------------------------------
__global__ __launch_bounds__(256) void pre_kernel(
    const float* __restrict__ Wv, const float* __restrict__ Wf,
    u16* __restrict__ WvT, u16* __restrict__ wfb,
    const float* __restrict__ dec, const float* __restrict__ kappa_in,
    const float* __restrict__ Wq, const float* __restrict__ bq,
    const float* __restrict__ bv,
    const float* __restrict__ Wb, const float* __restrict__ bb,
    const float* __restrict__ Wk, const float* __restrict__ bk,
    float* __restrict__ query_ws, float* __restrict__ beta_ws,
    float* __restrict__ kappa_out)
{
    __shared__ float sh[64 * 65];
    const int bid = blockIdx.x, tid = threadIdx.x;

    if (bid < 128) {                // ---- Wv transpose tile
        const int nt = bid & 15, kt = bid >> 4;
        for (int i = tid; i < 4096; i += 256) {
            const int kk = i >> 6, nn = i & 63;
            sh[kk * 65 + nn] = Wv[(size_t)(kt * 64 + kk) * IHD + nt * 64 + nn];
        }
        __syncthreads();
        for (int i = tid; i < 4096; i += 256) {
            const int nn = i >> 6, kk = i & 63;
            WvT[(size_t)(nt * 64 + nn) * 512 + kt * 64 + kk] = f2bf(sh[kk * 65 + nn]);
        }
        return;
    }
    if (bid == 128) {               // ---- Wf pack
        for (int i = tid; i < 8192; i += 256) {
            const int j   = i & 7;
            const int fr8 = (i >> 3) & 7;
            const int qd  = (i >> 6) & 3;
            const int ks  = (i >> 8) & 3;
            const int nn  = i >> 10;
            const int row = nn * 128 + ks * 32 + qd * 8 + j;
            wfb[i] = f2bf(Wf[row * NHEADS + fr8]);
        }
        return;
    }
    // ---- prep
    const int p = bid - 129;
    const int b = p & 31, y = p >> 5;
    float* s_dec = sh;
    float* s_red = sh + DE;
    for (int i = tid; i < DE; i += 256) s_dec[i] = dec[b * DE + i];
    __syncthreads();

    if (y < 32) {
        const int cl = tid & 31, kg = tid >> 5;
        const int col = y * 32 + cl;
        float a = 0.f;
        const float* w = Wq + col;
        #pragma unroll 4
        for (int k = kg * 128; k < kg * 128 + 128; ++k)
            a = fmaf(s_dec[k], w[(size_t)k * IHD], a);
        s_red[tid] = a;
        __syncthreads();
        if (tid < 32) {
            float s = 0.f;
            #pragma unroll
            for (int i = 0; i < 8; ++i) s += s_red[i * 32 + tid];
            query_ws[(size_t)b * IHD + col] = s + bq[col] + bv[col];
        }
    } else {
        const int h = tid & 7, kg = tid >> 3;
        float ab = 0.f, ak = 0.f;
        for (int k = kg * 32; k < kg * 32 + 32; ++k) {
            const float d = s_dec[k];
            ab = fmaf(d, Wb[k * NHEADS + h], ab);
            ak = fmaf(d, Wk[k * NHEADS + h], ak);
        }
        s_red[tid] = ab;
        __syncthreads();
        for (int off = 128; off >= 8; off >>= 1) {
            if (tid < off) s_red[tid] += s_red[tid + off];
            __syncthreads();
        }
        const float abT = (tid < 8) ? s_red[tid] : 0.f;
        __syncthreads();
        s_red[tid] = ak;
        __syncthreads();
        for (int off = 128; off >= 8; off >>= 1) {
            if (tid < off) s_red[tid] += s_red[tid + off];
            __syncthreads();
        }
        if (tid < 8) {
            beta_ws[b * NHEADS + tid]   = softplus_f(bb[tid] + abT);
            kappa_out[b * NHEADS + tid] = kappa_in[b * NHEADS + tid]
                                        + softplus_f(bk[tid] + s_red[tid]);
        }
    }
}

// ---------------------------------------------------------------------------
// Main fused kernel: BM=256 x BN=256 tile, 512 threads (8 waves, 4wr x 2wc,
// wave tile 64x128, acc[4][8]). LDS bytes per output cut 33% vs 128x128.
// ROUND-11 FIX vs round 10: A tile is 16384 u16 (32 KB), so B base is
// Ab + 16384 (round 10 had +32768 u16 = +64 KB -> buffers overlapped tT,
// s_score and overran the LDS allocation -> corruption).
// LDS map: buf0 [A 0-32K | B 32-64K] | buf1 [A 64-96K | B 96-128K] |
//          tT(64K) aliases buf1 | s_score 128K-136K.  Grid 256 = 1 block/CU.
// Sync schedule = 1:1 transplant of the proven round-7 one (counted vmcnt(8),
// never 0 mid-loop; barriers A/B per kt; C/D per epilogue slice).
// ---------------------------------------------------------------------------
#define BM 256

__global__ __launch_bounds__(512, 1) void gemm_score_ctx_kernel(
    const float* __restrict__ enc, u16* __restrict__ encb,
    const u16* __restrict__ wvT,
    const u16* __restrict__ wfb2, const float* __restrict__ bf_g,
    const float* __restrict__ mask, const float* __restrict__ query_ws,
    const float* __restrict__ beta_ws, const float* __restrict__ kappa_out,
    float* __restrict__ score_out, float* __restrict__ ctx_part)
{
    __shared__ __align__(16) unsigned char smem[139264];
    u16*   tT      = (u16*)(smem + 65536);     // aliases buf1
    float* s_score = (float*)(smem + 131072);

    const int tid  = threadIdx.x;
    const int m0   = blockIdx.x * BM;
    const int b    = blockIdx.x >> 3;           // 8 m-tiles per batch
    const int scb  = blockIdx.x & 7;            // 2 ctx chunks per block
    const int lane = tid & 63;
    const int w    = tid >> 6;                  // 0..7
    const int wr   = w >> 1, wc = w & 1;        // 4 x 2 wave grid
    const int fr   = lane & 15, quad = lane >> 4;

    // ---- prologue: convert own 256x512 enc rows fp32 -> bf16 (global)
    {
        const float4* src = (const float4*)enc + (size_t)m0 * 128;
        u16x8* dst = (u16x8*)(encb + (size_t)m0 * 512);
        #pragma unroll 4
        for (int i = tid; i < 16384; i += 512) {
            const float4 a = src[i * 2], b2 = src[i * 2 + 1];
            u16x8 o;
            o[0] = f2bf(a.x);  o[1] = f2bf(a.y);  o[2] = f2bf(a.z);  o[3] = f2bf(a.w);
            o[4] = f2bf(b2.x); o[5] = f2bf(b2.y); o[6] = f2bf(b2.z); o[7] = f2bf(b2.w);
            dst[i] = o;
        }
        asm volatile("s_waitcnt vmcnt(0)" ::: "memory");
        __builtin_amdgcn_sched_barrier(0);
        __builtin_amdgcn_s_barrier();   // all waves' stores in L2 before staging
    }

    // staging constants: 2048 chunks of 16B per 256x64 tile, 4 r-steps
    int mA[4], csA[4];
    #pragma unroll
    for (int r = 0; r < 4; ++r) {
        const int c = r * 512 + tid;
        mA[r]  = c >> 3;
        csA[r] = (c & 7) ^ (mA[r] & 7);
    }

    // stage A(256x64)+B(256x64) bf16 tiles for (pair pp2, k-step kt2):
    // 8 global_load_lds per thread
    auto stage = [&](int sel, int pp2, int kt2) {
        u16* Ab = (u16*)(smem + sel * 65536);
        u16* Bb = Ab + 16384;                  // A tile = 16384 u16 = 32 KB
        const size_t aoff = (size_t)kt2 * 64;
        const size_t boff = (size_t)pp2 * (256 * 512) + (size_t)kt2 * 64;
        #pragma unroll
        for (int r = 0; r < 4; ++r) {
            async_cp16(Ab + (r * 512 + (tid & 448)) * 8,
                       encb + (size_t)(m0 + mA[r]) * 512 + aoff + csA[r] * 8);
            async_cp16(Bb + (size_t)(r * 512 + (tid & 448)) * 8,
                       wvT + (size_t)mA[r] * 512 + boff + csA[r] * 8);
        }
    };

    floatx4 acc2[2] = {};

    stage(0, 0, 0);

    for (int pp = 0; pp < 4; ++pp) {
        floatx4 acc[4][8] = {};

        #pragma unroll
        for (int kt = 0; kt < 8; ++kt) {
            if (kt < 7)       stage((kt + 1) & 1, pp, kt + 1);
            else if (pp < 3)  stage(0, pp + 1, 0);
            // uniform counted wait: current tile's 8 landed, next's 8 flying
            if (kt == 7 && pp == 3) {
                asm volatile("s_waitcnt vmcnt(0)" ::: "memory");
            } else {
                asm volatile("s_waitcnt vmcnt(8)" ::: "memory");
            }
            __builtin_amdgcn_sched_barrier(0);
            __builtin_amdgcn_s_barrier();          // A: tile kt landed

            const u16* Ab = (const u16*)(smem + (kt & 1) * 65536);
            const u16* Bb = Ab + 16384;            // fixed offset
            __builtin_amdgcn_s_setprio(1);
            #pragma unroll
            for (int s2 = 0; s2 < 2; ++s2) {
                bf16x8 af[4], bfr[8];
                #pragma unroll
                for (int mt = 0; mt < 4; ++mt) {
                    const int ma = wr * 64 + mt * 16 + fr;
                    const int ca = (s2 * 4 + quad) ^ (ma & 7);
                    af[mt] = *(const bf16x8*)&Ab[ma * 64 + ca * 8];
                }
                #pragma unroll
                for (int nt = 0; nt < 8; ++nt) {
                    const int nb = wc * 128 + nt * 16 + fr;
                    const int cb = (s2 * 4 + quad) ^ (nb & 7);
                    bfr[nt] = *(const bf16x8*)&Bb[nb * 64 + cb * 8];
                }
                #pragma unroll
                for (int mt = 0; mt < 4; ++mt)
                    #pragma unroll
                    for (int nt = 0; nt < 8; ++nt)
                        acc[mt][nt] = __builtin_amdgcn_mfma_f32_16x16x32_bf16(
                            af[mt], bfr[nt], acc[mt][nt], 0, 0, 0);
            }
            __builtin_amdgcn_s_setprio(0);
            __builtin_amdgcn_sched_barrier(0);
            __builtin_amdgcn_s_barrier();          // B: buf (kt&1) free
        }

        // ---- epilogue: two 128-col slices of this pair
        #pragma unroll
        for (int s = 0; s < 2; ++s) {
            const int n0 = pp * 256 + s * 128;
            if (wc == s) {
                // this wave's 8 nt-columns are exactly slice s's 128 cols
                float qv[8];
                #pragma unroll
                for (int nt = 0; nt < 8; ++nt)
                    qv[nt] = query_ws[(size_t)b * IHD + n0 + nt * 16 + fr];
                #pragma unroll
                for (int mt = 0; mt < 4; ++mt) {
                    #pragma unroll
                    for (int nt = 0; nt < 8; ++nt) {
                        const int col = nt * 16 + fr;   // slice-local 0..127
                        #pragma unroll
                        for (int reg = 0; reg < 4; ++reg) {
                            const int row = wr * 64 + mt * 16 + quad * 4 + reg;
                            ((__bf16*)tT)[row * 128 + (col ^ ((row & 7) << 3))] =
                                (__bf16)tanh_fast(acc[mt][nt][reg] + qv[nt]);
                        }
                    }
                }
            }
            asm volatile("s_waitcnt lgkmcnt(0)" ::: "memory");
            __builtin_amdgcn_sched_barrier(0);
            __builtin_amdgcn_s_barrier();          // C: tT visible (all waves)

            // stage-2: P += t(256x128) @ Wf_slice(128x8), all 8 waves
            bf16x8 wfr[4];
            #pragma unroll
            for (int ks = 0; ks < 4; ++ks)
                wfr[ks] = *(const bf16x8*)&wfb2[(((pp * 2 + s) * 4 + ks) * 4
                                                 + quad) * 64 + (fr & 7) * 8];
            #pragma unroll
            for (int t = 0; t < 2; ++t) {
                const int row = w * 32 + t * 16 + fr;   // 0..255
                #pragma unroll
                for (int ks = 0; ks < 4; ++ks) {
                    const bf16x8 ta = *(const bf16x8*)
                        &tT[row * 128 + ((ks * 32 + quad * 8) ^ ((row & 7) << 3))];
                    acc2[t] = __builtin_amdgcn_mfma_f32_16x16x32_bf16(
                        ta, wfr[ks], acc2[t], 0, 0, 0);
                }
            }
            __builtin_amdgcn_sched_barrier(0);
            __builtin_amdgcn_s_barrier();          // D: tT reads done
        }
    }

    // ---- score: softplus(P + bf) * mask * exp(-beta*(kappa-u)^2)
    if (fr < NHEADS) {
        const float bfh = bf_g[fr];
        const float bet = beta_ws[b * NHEADS + fr];
        const float kap = kappa_out[b * NHEADS + fr];
        #pragma unroll
        for (int t = 0; t < 2; ++t) {
            #pragma unroll
            for (int reg = 0; reg < 4; ++reg) {
                const int row  = w * 32 + t * 16 + quad * 4 + reg;  // 0..255
                const int grow = m0 + row;
                const int s = grow & 2047;
                const float alpha = softplus_f(acc2[t][reg] + bfh) * mask[grow];
                const float du = kap - (float)s;
                const float v = alpha * __expf(-bet * du * du);
                score_out[(size_t)grow * NHEADS + fr] = v;
                s_score[row * NHEADS + fr] = v;
            }
        }
    }
    asm volatile("s_waitcnt lgkmcnt(0)" ::: "memory");
    __builtin_amdgcn_s_barrier();

    // ---- fused context partial: wave = (head-pair hp, s-half sh).
    //      part[scb*2+sh][b][2hp..2hp+1][e] over 128 rows, 16-deep batching.
    {
        const int hp = w & 3, sh = w >> 2;
        float acc0[8] = {}, acc1[8] = {};
        const u16* ep = encb + (size_t)(m0 + sh * 128) * 512 + lane * 8;
        for (int s0 = 0; s0 < 128; s0 += 16) {
            u16x8 ev[16];
            #pragma unroll
            for (int u = 0; u < 16; ++u)
                ev[u] = *(const u16x8*)(ep + (size_t)(s0 + u) * 512);
            #pragma unroll
            for (int u = 0; u < 16; ++u) {
                const float2 sc2 = *(const float2*)
                    &s_score[(sh * 128 + s0 + u) * NHEADS + 2 * hp];
                #pragma unroll
                for (int j = 0; j < 8; ++j) {
                    const float e = bf2f(ev[u][j]);
                    acc0[j] = fmaf(sc2.x, e, acc0[j]);
                    acc1[j] = fmaf(sc2.y, e, acc1[j]);
                }
            }
        }
        const int e8 = lane * 8;
        const int sc2i = scb * 2 + sh;             // 0..15, 128-row chunks
        float* outp = ctx_part + ((size_t)sc2i * BSZ + b) * (NHEADS * ENCD);
        *(float4*)&outp[(2 * hp + 0) * ENCD + e8]     = make_float4(acc0[0], acc0[1], acc0[2], acc0[3]);
        *(float4*)&outp[(2 * hp + 0) * ENCD + e8 + 4] = make_float4(acc0[4], acc0[5], acc0[6], acc0[7]);
        *(float4*)&outp[(2 * hp + 1) * ENCD + e8]     = make_float4(acc1[0], acc1[1], acc1[2], acc1[3]);
        *(float4*)&outp[(2 * hp + 1) * ENCD + e8 + 4] = make_float4(acc1[4], acc1[5], acc1[6], acc1[7]);
    }
}

// ---------------------------------------------------------------------------
// ctx_ws[i] = sum_sc part[sc][i]   (i < 131072)
// ---------------------------------------------------------------------------
__global__ __launch_bounds__(256) void ctx_reduce_kernel(
    const float* __restrict__ part, float* __restrict__ ctx_ws)
{
    const int i = blockIdx.x * 256 + threadIdx.x;
    float a = 0.f;
    #pragma unroll
    for (int sc = 0; sc < 16; ++sc)
        a += part[(size_t)sc * 131072 + i];
    ctx_ws[i] = a;
}

// ---------------------------------------------------------------------------
// out_ctx[b,j] += ctx[b, k0..k0+128] @ Wfc[k0..k0+128, j]  (+bfc at ks==0)
// grid (16, 32): 512 blocks = 2/CU.
// ---------------------------------------------------------------------------
__global__ __launch_bounds__(256) void final_kernel(
    const float* __restrict__ ctx_ws, const float* __restrict__ Wfc,
    const float* __restrict__ bfc, float* __restrict__ out_ctx)
{
    __shared__ float s_ctx[32][128];
    const int jc = blockIdx.x, ks = blockIdx.y, tid = threadIdx.x;
    const int jl = tid & 31, bg = tid >> 5;
    const int j = jc * 32 + jl;
    const int k0 = ks * 128;

    for (int i = tid; i < 32 * 128; i += 256) {
        const int bb2 = i >> 7, kk = i & 127;
        s_ctx[bb2][kk] = ctx_ws[(size_t)bb2 * (NHEADS * ENCD) + k0 + kk];
    }
    __syncthreads();

    float a0 = 0.f, a1 = 0.f, a2 = 0.f, a3 = 0.f;
    for (int kk = 0; kk < 128; ++kk) {
        const float wv = Wfc[(size_t)(k0 + kk) * ENCD + j];
        a0 = fmaf(s_ctx[bg * 4 + 0][kk], wv, a0);
        a1 = fmaf(s_ctx[bg * 4 + 1][kk], wv, a1);
        a2 = fmaf(s_ctx[bg * 4 + 2][kk], wv, a2);
        a3 = fmaf(s_ctx[bg * 4 + 3][kk], wv, a3);
    }
    const float bias = (ks == 0) ? bfc[j] : 0.0f;
    atomicAdd(&out_ctx[(bg * 4 + 0) * ENCD + j], a0 + bias);
    atomicAdd(&out_ctx[(bg * 4 + 1) * ENCD + j], a1 + bias);
    atomicAdd(&out_ctx[(bg * 4 + 2) * ENCD + j], a2 + bias);
    atomicAdd(&out_ctx[(bg * 4 + 3) * ENCD + j], a3 + bias);
}

// ---------------------------------------------------------------------------
extern "C" void kernel_launch(void* const* d_in, const int* in_sizes, int n_in,
                              void* d_out, int out_size, void* d_ws, size_t ws_size,
                              hipStream_t stream)
{
    const float* enc   = (const float*)d_in[0];
    const float* dec   = (const float*)d_in[1];
    const float* kapin = (const float*)d_in[2];
    const float* mask  = (const float*)d_in[3];
    const float* Wv    = (const float*)d_in[4];
    const float* bv    = (const float*)d_in[5];
    const float* Wq    = (const float*)d_in[6];
    const float* bq    = (const float*)d_in[7];
    const float* Wf    = (const float*)d_in[8];
    const float* bf    = (const float*)d_in[9];
    const float* Wb    = (const float*)d_in[10];
    const float* bb    = (const float*)d_in[11];
    const float* Wk    = (const float*)d_in[12];
    const float* bk    = (const float*)d_in[13];
    const float* Wfc   = (const float*)d_in[14];
    const float* bfc   = (const float*)d_in[15];

    // outputs: context(32*512) | kappa(32*8) | score(32*2048*8)
    float* out       = (float*)d_out;
    float* out_ctx   = out;
    float* out_kappa = out + 16384;
    float* out_score = out + 16640;

    // workspace layout (bytes)
    char* w = (char*)d_ws;
    u16*   enc_bf   = (u16*)w;                     // 67108864 B
    float* ctx_part = (float*)(w + 67108864);      //  8388608 B
    u16*   wvT      = (u16*)(w + 75497472);        //  1048576 B
    float* q_ws     = (float*)(w + 76546048);      //   131072 B
    float* beta_ws  = (float*)(w + 76677120);      //     1024 B
    float* ctx_ws   = (float*)(w + 76678144);      //   524288 B
    u16*   wfb      = (u16*)(w + 77202432);        //    16400 B (16384 used)
                                                   // total 77218832 B

    hipMemsetAsync(out_ctx, 0, 16384 * sizeof(float), stream);

    pre_kernel<<<dim3(128 + 1 + 1056), dim3(256), 0, stream>>>(
        Wv, Wf, wvT, wfb,
        dec, kapin, Wq, bq, bv, Wb, bb, Wk, bk, q_ws, beta_ws, out_kappa);

    gemm_score_ctx_kernel<<<dim3((BSZ * SEQL) / BM), dim3(512), 0, stream>>>(
        enc, enc_bf, wvT, wfb, bf, mask, q_ws, beta_ws, out_kappa,
        out_score, ctx_part);

    ctx_reduce_kernel<<<dim3(512), dim3(256), 0, stream>>>(ctx_part, ctx_ws);

    final_kernel<<<dim3(16, 32), dim3(256), 0, stream>>>(
        ctx_ws, Wfc, bfc, out_ctx);
}

// Round 12
// 393.223 us; speedup vs baseline: 1.5947x; 1.5947x over previous
//
#include <hip/hip_runtime.h>
#include <cstdint>
#include <cstddef>

#define BSZ    32
#define SEQL   2048
#define ENCD   512
#define DE     1024   // DEC + ENC
#define NHEADS 8
#define IHD    1024   // INTERM * HEADS

typedef unsigned short u16;
typedef __bf16 bf16x8 __attribute__((ext_vector_type(8)));
typedef float floatx4 __attribute__((ext_vector_type(4)));
typedef unsigned short u16x8 __attribute__((ext_vector_type(8)));

__device__ __forceinline__ u16 f2bf(float f) {
    unsigned int u = __float_as_uint(f);
    u = (u + 0x7FFFu + ((u >> 16) & 1u)) >> 16;   // RNE
    return (u16)u;
}
__device__ __forceinline__ float bf2f(u16 v) {
    return __uint_as_float(((unsigned int)v) << 16);
}
__device__ __forceinline__ float softplus_f(float x) {
    return fmaxf(x, 0.0f) + log1pf(__expf(-fabsf(x)));
}
__device__ __forceinline__ float tanh_fast(float x) {
    const float e = __expf(2.0f * x);
    return 1.0f - 2.0f / (e + 1.0f);
}
__device__ __forceinline__ void async_cp16(u16* lds, const u16* g) {
    __builtin_amdgcn_global_load_lds(
        (const __attribute__((address_space(1))) unsigned int*)g,
        (__attribute__((address_space(3))) unsigned int*)lds, 16, 0, 0);
}

// ---------------------------------------------------------------------------
// Producer kernel:
//   bid <  128 : WvT[n][k] = bf16(Wv[k][n]) via 64x64 LDS tile transpose
//   bid == 128 : Wf -> bf16 packed in MFMA B-fragment order
//   bid >  128 : prep (query_ws = dec@Wq+bq+bv, beta, kappa), 32x33 blocks
// ---------------------------------------------------------------------------
__global__ __launch_bounds__(256) void pre_kernel(
    const float* __restrict__ Wv, const float* __restrict__ Wf,
    u16* __restrict__ WvT, u16* __restrict__ wfb,
    const float* __restrict__ dec, const float* __restrict__ kappa_in,
    const float* __restrict__ Wq, const float* __restrict__ bq,
    const float* __restrict__ bv,
    const float* __restrict__ Wb, const float* __restrict__ bb,
    const float* __restrict__ Wk, const float* __restrict__ bk,
    float* __restrict__ query_ws, float* __restrict__ beta_ws,
    float* __restrict__ kappa_out)
{
    __shared__ float sh[64 * 65];
    const int bid = blockIdx.x, tid = threadIdx.x;

    if (bid < 128) {                // ---- Wv transpose tile
        const int nt = bid & 15, kt = bid >> 4;
        for (int i = tid; i < 4096; i += 256) {
            const int kk = i >> 6, nn = i & 63;
            sh[kk * 65 + nn] = Wv[(size_t)(kt * 64 + kk) * IHD + nt * 64 + nn];
        }
        __syncthreads();
        for (int i = tid; i < 4096; i += 256) {
            const int nn = i >> 6, kk = i & 63;
            WvT[(size_t)(nt * 64 + nn) * 512 + kt * 64 + kk] = f2bf(sh[kk * 65 + nn]);
        }
        return;
    }
    if (bid == 128) {               // ---- Wf pack
        for (int i = tid; i < 8192; i += 256) {
            const int j   = i & 7;
            const int fr8 = (i >> 3) & 7;
            const int qd  = (i >> 6) & 3;
            const int ks  = (i >> 8) & 3;
            const int nn  = i >> 10;
            const int row = nn * 128 + ks * 32 + qd * 8 + j;
            wfb[i] = f2bf(Wf[row * NHEADS + fr8]);
        }
        return;
    }
    // ---- prep
    const int p = bid - 129;
    const int b = p & 31, y = p >> 5;
    float* s_dec = sh;
    float* s_red = sh + DE;
    for (int i = tid; i < DE; i += 256) s_dec[i] = dec[b * DE + i];
    __syncthreads();

    if (y < 32) {
        const int cl = tid & 31, kg = tid >> 5;
        const int col = y * 32 + cl;
        float a = 0.f;
        const float* w = Wq + col;
        #pragma unroll 8
        for (int k = kg * 128; k < kg * 128 + 128; ++k)
            a = fmaf(s_dec[k], w[(size_t)k * IHD], a);
        s_red[tid] = a;
        __syncthreads();
        if (tid < 32) {
            float s = 0.f;
            #pragma unroll
            for (int i = 0; i < 8; ++i) s += s_red[i * 32 + tid];
            query_ws[(size_t)b * IHD + col] = s + bq[col] + bv[col];
        }
    } else {
        const int h = tid & 7, kg = tid >> 3;
        float ab = 0.f, ak = 0.f;
        for (int k = kg * 32; k < kg * 32 + 32; ++k) {
            const float d = s_dec[k];
            ab = fmaf(d, Wb[k * NHEADS + h], ab);
            ak = fmaf(d, Wk[k * NHEADS + h], ak);
        }
        s_red[tid] = ab;
        __syncthreads();
        for (int off = 128; off >= 8; off >>= 1) {
            if (tid < off) s_red[tid] += s_red[tid + off];
            __syncthreads();
        }
        const float abT = (tid < 8) ? s_red[tid] : 0.f;
        __syncthreads();
        s_red[tid] = ak;
        __syncthreads();
        for (int off = 128; off >= 8; off >>= 1) {
            if (tid < off) s_red[tid] += s_red[tid + off];
            __syncthreads();
        }
        if (tid < 8) {
            beta_ws[b * NHEADS + tid]   = softplus_f(bb[tid] + abT);
            kappa_out[b * NHEADS + tid] = kappa_in[b * NHEADS + tid]
                                        + softplus_f(bk[tid] + s_red[tid]);
        }
    }
}

// ---------------------------------------------------------------------------
// Main fused kernel (round-9 structure, measured best 203us):
//  - prologue converts own 128 enc rows fp32->bf16 (unroll-4 pipelining),
//    drain, barrier.
//  - main loop: A+B via global_load_lds double-buffer, BK=64 (128B rows,
//    conflict-free XOR swizzle), counted vmcnt (never 0 mid-loop), setprio
//    around MFMA cluster. BM=128 -> 512 blocks = 2/CU (cross-block overlap
//    hides barrier waits; 256^2/1-block variants measured worse: spill).
//  - tail: score phase writes s_score only; then ONE coalesced 4KB global
//    store (removes 32B partial-line scatter, ~2x write amplification);
//    ctx partial with 16-deep load batching (latency fix, round 9).
// LDS: buf0 32K | buf1 32K | tT 32K aliases buf1 | s_score 4K = 68K.
// ---------------------------------------------------------------------------
#define BM 128

__global__ __launch_bounds__(256, 2) void gemm_score_ctx_kernel(
    const float* __restrict__ enc, u16* __restrict__ encb,
    const u16* __restrict__ wvT,
    const u16* __restrict__ wfb2, const float* __restrict__ bf_g,
    const float* __restrict__ mask, const float* __restrict__ query_ws,
    const float* __restrict__ beta_ws, const float* __restrict__ kappa_out,
    float* __restrict__ score_out, float* __restrict__ ctx_part)
{
    __shared__ __align__(16) unsigned char smem[69632];
    u16*   tT      = (u16*)(smem + 32768);     // aliases buf1
    float* s_score = (float*)(smem + 65536);

    const int tid  = threadIdx.x;
    const int m0   = blockIdx.x * BM;
    const int b    = blockIdx.x >> 4;           // 16 m-tiles per batch
    const int sc   = blockIdx.x & 15;           // seq chunk for ctx_part
    const int lane = tid & 63;
    const int w    = tid >> 6;
    const int wr   = w >> 1, wc = w & 1;
    const int fr   = lane & 15, quad = lane >> 4;

    // ---- prologue: convert own 128x512 enc rows fp32 -> bf16 (global)
    {
        const float4* src = (const float4*)enc + (size_t)m0 * 128;
        u16x8* dst = (u16x8*)(encb + (size_t)m0 * 512);
        #pragma unroll 4
        for (int i = tid; i < 8192; i += 256) {
            const float4 a = src[i * 2], b2 = src[i * 2 + 1];
            u16x8 o;
            o[0] = f2bf(a.x);  o[1] = f2bf(a.y);  o[2] = f2bf(a.z);  o[3] = f2bf(a.w);
            o[4] = f2bf(b2.x); o[5] = f2bf(b2.y); o[6] = f2bf(b2.z); o[7] = f2bf(b2.w);
            dst[i] = o;
        }
        asm volatile("s_waitcnt vmcnt(0)" ::: "memory");
        __builtin_amdgcn_sched_barrier(0);
        __builtin_amdgcn_s_barrier();   // all waves' stores in L2 before staging
    }

    // staging constants (8 chunks of 16B per 128x64 tile row-space)
    int mA[4], csA[4];
    #pragma unroll
    for (int r = 0; r < 4; ++r) {
        const int c = r * 256 + tid;
        mA[r]  = c >> 3;
        csA[r] = (c & 7) ^ (mA[r] & 7);
    }

    // stage A(128x64)+B(128x64) bf16 tile pair for flat iter it=(nn,kt):
    // 8 global_load_lds per thread
    auto stage = [&](int bufsel, int it) {
        u16* Ab = (u16*)(smem + bufsel * 32768);
        u16* Bb = Ab + 8192;
        const int nn2 = it >> 3, kt2 = it & 7;
        const size_t aoff = (size_t)kt2 * 64;
        const size_t boff = (size_t)nn2 * (128 * 512) + (size_t)kt2 * 64;
        #pragma unroll
        for (int r = 0; r < 4; ++r) {
            async_cp16(Ab + (r * 256 + (tid & 192)) * 8,
                       encb + (size_t)(m0 + mA[r]) * 512 + aoff + csA[r] * 8);
            async_cp16(Bb + (size_t)(r * 256 + (tid & 192)) * 8,
                       wvT + (size_t)mA[r] * 512 + boff + csA[r] * 8);
        }
    };

    floatx4 acc2[2] = {};

    stage(0, 0);

    for (int nn = 0; nn < 8; ++nn) {
        const int n0 = nn * 128;
        float qv[4];
        bf16x8 wfr[4];
        floatx4 acc[4][4] = {};

        #pragma unroll
        for (int kt = 0; kt < 8; ++kt) {
            const int it = nn * 8 + kt;
            if (kt < 7 || nn < 7)
                stage((it + 1) & 1, it + 1);
            if (kt == 0) {
                // epilogue operands; issued AFTER stage -> the 8 newest vm-ops
                #pragma unroll
                for (int nt = 0; nt < 4; ++nt)
                    qv[nt] = query_ws[(size_t)b * IHD + n0 + wc * 64 + nt * 16 + fr];
                #pragma unroll
                for (int ks = 0; ks < 4; ++ks)
                    wfr[ks] = *(const bf16x8*)&wfb2[((nn * 4 + ks) * 4 + quad) * 64
                                                    + (fr & 7) * 8];
            }
            // counted wait: only tile it must have landed.
            if (kt == 7 && nn == 7) {
                asm volatile("s_waitcnt vmcnt(0)" ::: "memory");
            } else if (kt == 0) {
                asm volatile("s_waitcnt vmcnt(16)" ::: "memory");
            } else {
                asm volatile("s_waitcnt vmcnt(8)" ::: "memory");
            }
            __builtin_amdgcn_sched_barrier(0);
            __builtin_amdgcn_s_barrier();          // A: tile it landed

            u16* Ab = (u16*)(smem + (it & 1) * 32768);
            u16* Bb = Ab + 8192;
            __builtin_amdgcn_s_setprio(1);
            #pragma unroll
            for (int s2 = 0; s2 < 2; ++s2) {
                bf16x8 af[4], bfr[4];
                #pragma unroll
                for (int mt = 0; mt < 4; ++mt) {
                    const int ma = wr * 64 + mt * 16 + fr;
                    const int ca = (s2 * 4 + quad) ^ (ma & 7);
                    af[mt] = *(const bf16x8*)&Ab[ma * 64 + ca * 8];
                }
                #pragma unroll
                for (int nt = 0; nt < 4; ++nt) {
                    const int nb = wc * 64 + nt * 16 + fr;
                    const int cb = (s2 * 4 + quad) ^ (nb & 7);
                    bfr[nt] = *(const bf16x8*)&Bb[nb * 64 + cb * 8];
                }
                #pragma unroll
                for (int mt = 0; mt < 4; ++mt)
                    #pragma unroll
                    for (int nt = 0; nt < 4; ++nt)
                        acc[mt][nt] = __builtin_amdgcn_mfma_f32_16x16x32_bf16(
                            af[mt], bfr[nt], acc[mt][nt], 0, 0, 0);
            }
            __builtin_amdgcn_s_setprio(0);
            __builtin_amdgcn_sched_barrier(0);
            __builtin_amdgcn_s_barrier();          // B: buf (it&1) free
        }

        // ---- epilogue A: t = tanh(value + query) -> tT (bf16, XOR-swizzled)
        // tT aliases buf1 (just consumed at kt=7; next-nn prefetch is in buf0)
        #pragma unroll
        for (int mt = 0; mt < 4; ++mt) {
            #pragma unroll
            for (int nt = 0; nt < 4; ++nt) {
                const int col = wc * 64 + nt * 16 + fr;
                #pragma unroll
                for (int reg = 0; reg < 4; ++reg) {
                    const int row = wr * 64 + mt * 16 + quad * 4 + reg;
                    ((__bf16*)tT)[row * 128 + (col ^ ((row & 7) << 3))] =
                        (__bf16)tanh_fast(acc[mt][nt][reg] + qv[nt]);
                }
            }
        }
        asm volatile("s_waitcnt lgkmcnt(0)" ::: "memory");
        __builtin_amdgcn_sched_barrier(0);
        __builtin_amdgcn_s_barrier();              // C: tT visible

        // ---- epilogue B: stage-2 MFMA  P += t(128x128) @ Wf_slice(128x8)
        #pragma unroll
        for (int t = 0; t < 2; ++t) {
            const int row = w * 32 + t * 16 + fr;
            #pragma unroll
            for (int ks = 0; ks < 4; ++ks) {
                const bf16x8 ta = *(const bf16x8*)
                    &tT[row * 128 + ((ks * 32 + quad * 8) ^ ((row & 7) << 3))];
                acc2[t] = __builtin_amdgcn_mfma_f32_16x16x32_bf16(ta, wfr[ks], acc2[t], 0, 0, 0);
            }
        }
        __builtin_amdgcn_sched_barrier(0);
        __builtin_amdgcn_s_barrier();              // D: tT reads done before
                                                   //    next nn stages buf1
    }

    // ---- score: softplus(P + bf) * mask * exp(-beta*(kappa-u)^2) -> s_score
    if (fr < NHEADS) {
        const float bfh = bf_g[fr];
        const float bet = beta_ws[b * NHEADS + fr];
        const float kap = kappa_out[b * NHEADS + fr];
        #pragma unroll
        for (int t = 0; t < 2; ++t) {
            #pragma unroll
            for (int reg = 0; reg < 4; ++reg) {
                const int row  = w * 32 + t * 16 + quad * 4 + reg;  // 0..127
                const int grow = m0 + row;
                const int s = grow & 2047;
                const float alpha = softplus_f(acc2[t][reg] + bfh) * mask[grow];
                const float du = kap - (float)s;
                s_score[row * NHEADS + fr] = alpha * __expf(-bet * du * du);
            }
        }
    }
    asm volatile("s_waitcnt lgkmcnt(0)" ::: "memory");
    __builtin_amdgcn_s_barrier();

    // ---- coalesced score store: one contiguous 4KB block (was a 32B
    //      partial-line scatter with ~2x write amplification)
    {
        const float4* src4 = (const float4*)s_score;
        float4* dst4 = (float4*)(score_out + (size_t)m0 * NHEADS);
        dst4[tid] = src4[tid];     // 256 threads x 16B = 4KB = 128x8 floats
    }

    // ---- fused context partial over this block's 128 rows:
    //      part[sc][b][h][e] = sum_s score[s,h] * enc[s,e]
    //      16-deep load batching (enc_bf re-read misses L2: 8MB/XCD > 4MB).
    {
        float acc0[8] = {}, acc1[8] = {};
        const u16* ep = encb + (size_t)m0 * 512 + lane * 8;
        for (int s0 = 0; s0 < 128; s0 += 16) {
            u16x8 ev[16];
            #pragma unroll
            for (int u = 0; u < 16; ++u)
                ev[u] = *(const u16x8*)(ep + (size_t)(s0 + u) * 512);
            #pragma unroll
            for (int u = 0; u < 16; ++u) {
                const float2 sc2 = *(const float2*)&s_score[(s0 + u) * NHEADS + 2 * w];
                #pragma unroll
                for (int j = 0; j < 8; ++j) {
                    const float e = bf2f(ev[u][j]);
                    acc0[j] = fmaf(sc2.x, e, acc0[j]);
                    acc1[j] = fmaf(sc2.y, e, acc1[j]);
                }
            }
        }
        const int e8 = lane * 8;
        float* outp = ctx_part + ((size_t)sc * BSZ + b) * (NHEADS * ENCD);
        *(float4*)&outp[(2 * w + 0) * ENCD + e8]     = make_float4(acc0[0], acc0[1], acc0[2], acc0[3]);
        *(float4*)&outp[(2 * w + 0) * ENCD + e8 + 4] = make_float4(acc0[4], acc0[5], acc0[6], acc0[7]);
        *(float4*)&outp[(2 * w + 1) * ENCD + e8]     = make_float4(acc1[0], acc1[1], acc1[2], acc1[3]);
        *(float4*)&outp[(2 * w + 1) * ENCD + e8 + 4] = make_float4(acc1[4], acc1[5], acc1[6], acc1[7]);
    }
}

// ---------------------------------------------------------------------------
// ctx_ws[i] = sum_sc part[sc][i]   (i < 131072)
// ---------------------------------------------------------------------------
__global__ __launch_bounds__(256) void ctx_reduce_kernel(
    const float* __restrict__ part, float* __restrict__ ctx_ws)
{
    const int i = blockIdx.x * 256 + threadIdx.x;
    float a = 0.f;
    #pragma unroll
    for (int sc = 0; sc < 16; ++sc)
        a += part[(size_t)sc * 131072 + i];
    ctx_ws[i] = a;
}

// ---------------------------------------------------------------------------
// out_ctx[b,j] += ctx[b, k0..k0+128] @ Wfc[k0..k0+128, j]  (+bfc at ks==0)
// grid (16, 32): 512 blocks = 2/CU.
// ---------------------------------------------------------------------------
__global__ __launch_bounds__(256) void final_kernel(
    const float* __restrict__ ctx_ws, const float* __restrict__ Wfc,
    const float* __restrict__ bfc, float* __restrict__ out_ctx)
{
    __shared__ float s_ctx[32][128];
    const int jc = blockIdx.x, ks = blockIdx.y, tid = threadIdx.x;
    const int jl = tid & 31, bg = tid >> 5;
    const int j = jc * 32 + jl;
    const int k0 = ks * 128;

    for (int i = tid; i < 32 * 128; i += 256) {
        const int bb2 = i >> 7, kk = i & 127;
        s_ctx[bb2][kk] = ctx_ws[(size_t)bb2 * (NHEADS * ENCD) + k0 + kk];
    }
    __syncthreads();

    float a0 = 0.f, a1 = 0.f, a2 = 0.f, a3 = 0.f;
    for (int kk = 0; kk < 128; ++kk) {
        const float wv = Wfc[(size_t)(k0 + kk) * ENCD + j];
        a0 = fmaf(s_ctx[bg * 4 + 0][kk], wv, a0);
        a1 = fmaf(s_ctx[bg * 4 + 1][kk], wv, a1);
        a2 = fmaf(s_ctx[bg * 4 + 2][kk], wv, a2);
        a3 = fmaf(s_ctx[bg * 4 + 3][kk], wv, a3);
    }
    const float bias = (ks == 0) ? bfc[j] : 0.0f;
    atomicAdd(&out_ctx[(bg * 4 + 0) * ENCD + j], a0 + bias);
    atomicAdd(&out_ctx[(bg * 4 + 1) * ENCD + j], a1 + bias);
    atomicAdd(&out_ctx[(bg * 4 + 2) * ENCD + j], a2 + bias);
    atomicAdd(&out_ctx[(bg * 4 + 3) * ENCD + j], a3 + bias);
}

// ---------------------------------------------------------------------------
extern "C" void kernel_launch(void* const* d_in, const int* in_sizes, int n_in,
                              void* d_out, int out_size, void* d_ws, size_t ws_size,
                              hipStream_t stream)
{
    const float* enc   = (const float*)d_in[0];
    const float* dec   = (const float*)d_in[1];
    const float* kapin = (const float*)d_in[2];
    const float* mask  = (const float*)d_in[3];
    const float* Wv    = (const float*)d_in[4];
    const float* bv    = (const float*)d_in[5];
    const float* Wq    = (const float*)d_in[6];
    const float* bq    = (const float*)d_in[7];
    const float* Wf    = (const float*)d_in[8];
    const float* bf    = (const float*)d_in[9];
    const float* Wb    = (const float*)d_in[10];
    const float* bb    = (const float*)d_in[11];
    const float* Wk    = (const float*)d_in[12];
    const float* bk    = (const float*)d_in[13];
    const float* Wfc   = (const float*)d_in[14];
    const float* bfc   = (const float*)d_in[15];

    // outputs: context(32*512) | kappa(32*8) | score(32*2048*8)
    float* out       = (float*)d_out;
    float* out_ctx   = out;
    float* out_kappa = out + 16384;
    float* out_score = out + 16640;

    // workspace layout (bytes)
    char* w = (char*)d_ws;
    u16*   enc_bf   = (u16*)w;                     // 67108864 B
    float* ctx_part = (float*)(w + 67108864);      //  8388608 B
    u16*   wvT      = (u16*)(w + 75497472);        //  1048576 B
    float* q_ws     = (float*)(w + 76546048);      //   131072 B
    float* beta_ws  = (float*)(w + 76677120);      //     1024 B
    float* ctx_ws   = (float*)(w + 76678144);      //   524288 B
    u16*   wfb      = (u16*)(w + 77202432);        //    16400 B (16384 used)
                                                   // total 77218832 B

    hipMemsetAsync(out_ctx, 0, 16384 * sizeof(float), stream);

    pre_kernel<<<dim3(128 + 1 + 1056), dim3(256), 0, stream>>>(
        Wv, Wf, wvT, wfb,
        dec, kapin, Wq, bq, bv, Wb, bb, Wk, bk, q_ws, beta_ws, out_kappa);

    gemm_score_ctx_kernel<<<dim3((BSZ * SEQL) / BM), dim3(256), 0, stream>>>(
        enc, enc_bf, wvT, wfb, bf, mask, q_ws, beta_ws, out_kappa,
        out_score, ctx_part);

    ctx_reduce_kernel<<<dim3(512), dim3(256), 0, stream>>>(ctx_part, ctx_ws);

    final_kernel<<<dim3(16, 32), dim3(256), 0, stream>>>(
        ctx_ws, Wfc, bfc, out_ctx);
}